// Round 2
// baseline (1172.781 us; speedup 1.0000x reference)
//
#include <hip/hip_runtime.h>
#include <hip/hip_bf16.h>

// Fused Swin window-attention: qkv GEMM + bias + mask + softmax + PV + proj
// in ONE kernel, bf16 MFMA (32x32x16), fp32 accum.
//
// Geometry: B_=16384 windows, N=49 (pad 64), C=128, H=4, d=32, nW=1024.
// Block = 8 windows sharing one mask row (bi = mw + 1024*batch). 256 thr.
// wave w (0..3) == head h == proj co-tile.

typedef __attribute__((ext_vector_type(8)))  short bf16x8;
typedef __attribute__((ext_vector_type(16))) float f32x16;

#define SCALE_QK 0.1767766952966369f  // 1/sqrt(32)

__device__ __forceinline__ unsigned short f2b(float f) {
    unsigned int x = __float_as_uint(f);
    unsigned int r = x + 0x7fffu + ((x >> 16) & 1u);   // RNE to bf16
    return (unsigned short)(r >> 16);
}
__device__ __forceinline__ float b2f(unsigned short u) {
    return __uint_as_float(((unsigned int)u) << 16);
}
__device__ __forceinline__ unsigned int pk2(float lo, float hi) {
    return ((unsigned int)f2b(hi) << 16) | (unsigned int)f2b(lo);
}
// XOR swizzle: spreads 16B granules across banks per row (bandwidth-minimum)
__device__ __forceinline__ unsigned swzoff(unsigned row, unsigned colb, unsigned strideb) {
    return row * strideb + (colb ^ ((row & 7u) << 4));
}
__device__ __forceinline__ f32x16 mfma16(bf16x8 a, bf16x8 b, f32x16 c) {
    return __builtin_amdgcn_mfma_f32_32x32x16_bf16(a, b, c, 0, 0, 0);
}
__device__ __forceinline__ bf16x8 ld8(const unsigned short* base, unsigned off) {
    return *reinterpret_cast<const bf16x8*>(reinterpret_cast<const char*>(base) + off);
}
__device__ __forceinline__ void st64(unsigned short* base, unsigned off, unsigned w0, unsigned w1) {
    uint2 v; v.x = w0; v.y = w1;
    *reinterpret_cast<uint2*>(reinterpret_cast<char*>(base) + off) = v;
}

// ---------------- pre-kernel: bf16 weights + expanded rel-pos bias ----------
__global__ void wa_pre(const float* __restrict__ qkv_w,
                       const float* __restrict__ proj_w,
                       const float* __restrict__ btab,
                       unsigned short* __restrict__ Wb,
                       unsigned short* __restrict__ Pb,
                       unsigned short* __restrict__ Bt) {
    int i = blockIdx.x * 256 + threadIdx.x;
    if (i < 49152) {                      // qkv_w [384][128] -> bf16 row-major
        Wb[i] = f2b(qkv_w[i]);
    } else if (i < 65536) {               // proj_w [128][128]
        Pb[i - 49152] = f2b(proj_w[i - 49152]);
    } else if (i < 65536 + 4 * 49 * 64) { // biasT[h][m][n] = table[rpi(n,m)][h]
        int j  = i - 65536;
        int n  = j & 63;
        int hm = j >> 6;
        int m  = hm % 49;
        int h  = hm / 49;
        unsigned short v = 0;
        if (n < 49) {
            int dy = n / 7 - m / 7 + 6;
            int dx = n % 7 - m % 7 + 6;
            v = f2b(btab[(dy * 13 + dx) * 4 + h]);
        }
        Bt[j] = v;
    }
}

// ---------------- main fused kernel ----------------------------------------
__global__ __launch_bounds__(256, 2)
void wa_main(const float* __restrict__ x,
             const float* __restrict__ mask,
             const float* __restrict__ qkv_b,
             const float* __restrict__ proj_b,
             const unsigned short* __restrict__ Wb,
             const unsigned short* __restrict__ Pb,
             const unsigned short* __restrict__ Bt,
             float* __restrict__ out) {
    // LDS: 75776 B total -> 2 blocks/CU
    __shared__ alignas(16) unsigned short sQK[64 * 256];  // rows n|m, [Q(128)|K(128)] bf16, stride 512B, swz
    __shared__ alignas(16) unsigned short sVt[128 * 64];  // V^T [ci][m], stride 128B, swz
    __shared__ alignas(16) unsigned short sXO[64 * 128];  // X (phase 1) then OH (phase 3), stride 256B, swz
    __shared__ alignas(16) unsigned short sMask[64 * 64]; // mask^T [m][n] bf16
    __shared__ float sQB[384];
    __shared__ float sPB[128];

    const int tid = threadIdx.x;
    const int w   = tid >> 6;        // wave = head = co-tile
    const int l31 = tid & 31;
    const int hi  = (tid >> 5) & 1;

    const int mw    = blockIdx.x & 1023;  // mask index
    const int bhalf = blockIdx.x >> 10;   // 0..1 (batch halves)

    for (int i = tid; i < 384;  i += 256) sQB[i] = qkv_b[i];
    for (int i = tid; i < 128;  i += 256) sPB[i] = proj_b[i];
    for (int i = tid; i < 4096; i += 256) sMask[i] = 0;
    __syncthreads();
    for (int j = tid; j < 2401; j += 256) {       // coalesced read, LDS transpose
        int n = j / 49;
        int m = j - n * 49;
        sMask[(m << 6) + n] = f2b(mask[mw * 2401 + j]);
    }

    // weight pointers: lane reads 16B at row (32w+l31), col (16kc+8hi)
    const unsigned short* Wq = Wb + (32 * w + l31) * 128 + 8 * hi;
    const unsigned short* Wk = Wq + 128 * 128;
    const unsigned short* Wv = Wq + 256 * 128;
    const unsigned short* Pr = Pb + (32 * w + l31) * 128 + 8 * hi;

#pragma unroll 1
    for (int t = 0; t < 8; ++t) {
        const int bi = mw + 1024 * (bhalf * 8 + t);
        __syncthreads();                 // prev proj reads of sXO done; mask visible
        asm volatile("" ::: "memory");   // keep per-iteration loads in the loop

        // ---- phase A: stage X window -> bf16 LDS (rows 49..63 zero) ----
        const float* xg = x + (size_t)bi * 6272;
        for (int c = tid; c < 1024; c += 256) {
            int row = c >> 4, cc = c & 15;
            union { unsigned short u[8]; bf16x8 v; } pkd;
            if (row < 49) {
                const float* src = xg + row * 128 + cc * 8;
                float4 a0 = *reinterpret_cast<const float4*>(src);
                float4 a1 = *reinterpret_cast<const float4*>(src + 4);
                pkd.u[0] = f2b(a0.x); pkd.u[1] = f2b(a0.y);
                pkd.u[2] = f2b(a0.z); pkd.u[3] = f2b(a0.w);
                pkd.u[4] = f2b(a1.x); pkd.u[5] = f2b(a1.y);
                pkd.u[6] = f2b(a1.z); pkd.u[7] = f2b(a1.w);
            } else {
#pragma unroll
                for (int k2 = 0; k2 < 8; ++k2) pkd.u[k2] = 0;
            }
            *reinterpret_cast<bf16x8*>(reinterpret_cast<char*>(sXO) +
                                       swzoff(row, cc * 16, 256)) = pkd.v;
        }
        __syncthreads();

        // ---- phase B: QKV GEMM. Q,K as W·X^T (D[o][n]); V as X·Wv^T (D[n][o])
        f32x16 aq0, aq1, ak0, ak1, av0, av1;
#pragma unroll
        for (int i2 = 0; i2 < 16; ++i2) {
            aq0[i2] = 0.f; aq1[i2] = 0.f; ak0[i2] = 0.f;
            ak1[i2] = 0.f; av0[i2] = 0.f; av1[i2] = 0.f;
        }
#pragma unroll
        for (int kc = 0; kc < 8; ++kc) {
            bf16x8 fq = *reinterpret_cast<const bf16x8*>(Wq + kc * 16);
            bf16x8 fk = *reinterpret_cast<const bf16x8*>(Wk + kc * 16);
            bf16x8 fv = *reinterpret_cast<const bf16x8*>(Wv + kc * 16);
            unsigned cb = (16 * kc + 8 * hi) * 2;
            bf16x8 x0 = ld8(sXO, swzoff(l31,      cb, 256));
            bf16x8 x1 = ld8(sXO, swzoff(32 + l31, cb, 256));
            aq0 = mfma16(fq, x0, aq0);  aq1 = mfma16(fq, x1, aq1);
            ak0 = mfma16(fk, x0, ak0);  ak1 = mfma16(fk, x1, ak1);
            av0 = mfma16(x0, fv, av0);  av1 = mfma16(x1, fv, av1);
        }
        {   // epilogue: +bias (Q also *scale), pack 4 consecutive -> b64 stores
            float vb = sQB[256 + 32 * w + l31];
#pragma unroll
            for (int g = 0; g < 4; ++g) {
                int ob = 8 * g + 4 * hi;
                int oq = 32 * w + ob;            // Q element index in row
                float b0 = sQB[oq + 0], b1 = sQB[oq + 1], b2 = sQB[oq + 2], b3 = sQB[oq + 3];
                st64(sQK, swzoff(l31, oq * 2, 512),
                     pk2((aq0[4*g+0]+b0)*SCALE_QK, (aq0[4*g+1]+b1)*SCALE_QK),
                     pk2((aq0[4*g+2]+b2)*SCALE_QK, (aq0[4*g+3]+b3)*SCALE_QK));
                st64(sQK, swzoff(32 + l31, oq * 2, 512),
                     pk2((aq1[4*g+0]+b0)*SCALE_QK, (aq1[4*g+1]+b1)*SCALE_QK),
                     pk2((aq1[4*g+2]+b2)*SCALE_QK, (aq1[4*g+3]+b3)*SCALE_QK));
                int ok = 128 + oq;               // K element index in row
                float c0 = sQB[ok + 0], c1 = sQB[ok + 1], c2 = sQB[ok + 2], c3 = sQB[ok + 3];
                st64(sQK, swzoff(l31, ok * 2, 512),
                     pk2(ak0[4*g+0]+c0, ak0[4*g+1]+c1), pk2(ak0[4*g+2]+c2, ak0[4*g+3]+c3));
                st64(sQK, swzoff(32 + l31, ok * 2, 512),
                     pk2(ak1[4*g+0]+c0, ak1[4*g+1]+c1), pk2(ak1[4*g+2]+c2, ak1[4*g+3]+c3));
                // V^T: row ci = 32w+l31 (lane-fixed), cols m = ob..ob+3 (+32)
                st64(sVt, swzoff(32 * w + l31, ob * 2, 128),
                     pk2(av0[4*g+0]+vb, av0[4*g+1]+vb), pk2(av0[4*g+2]+vb, av0[4*g+3]+vb));
                st64(sVt, swzoff(32 * w + l31, (32 + ob) * 2, 128),
                     pk2(av1[4*g+0]+vb, av1[4*g+1]+vb), pk2(av1[4*g+2]+vb, av1[4*g+3]+vb));
            }
        }
        __syncthreads();

        // ---- phase C: attention for head h=w. S^T = K·Q^T (swapped). ------
        f32x16 st2[2][2];                 // [tm][tn]: S^T[m][n], m=row per-reg, n=l31+32tn
#pragma unroll
        for (int a2 = 0; a2 < 2; ++a2)
#pragma unroll
            for (int b2 = 0; b2 < 2; ++b2)
#pragma unroll
                for (int i2 = 0; i2 < 16; ++i2) st2[a2][b2][i2] = 0.f;
        {
            bf16x8 qf[2][2], kf[2][2];
#pragma unroll
            for (int tt = 0; tt < 2; ++tt)
#pragma unroll
                for (int kc = 0; kc < 2; ++kc) {
                    qf[tt][kc] = ld8(sQK, swzoff(l31 + 32 * tt, (32 * w + 16 * kc + 8 * hi) * 2, 512));
                    kf[tt][kc] = ld8(sQK, swzoff(l31 + 32 * tt, (128 + 32 * w + 16 * kc + 8 * hi) * 2, 512));
                }
#pragma unroll
            for (int tm = 0; tm < 2; ++tm)
#pragma unroll
                for (int tn = 0; tn < 2; ++tn)
#pragma unroll
                    for (int kc = 0; kc < 2; ++kc)
                        st2[tm][tn] = mfma16(kf[tm][kc], qf[tn][kc], st2[tm][tn]);
        }
        // softmax over m (rows), fully in-register; scale folded into Q
#pragma unroll
        for (int tn = 0; tn < 2; ++tn) {
            const int nn = l31 + 32 * tn;
            float mx = -3.0e30f;
#pragma unroll
            for (int tm = 0; tm < 2; ++tm)
#pragma unroll
                for (int r = 0; r < 16; ++r) {
                    int m = 32 * tm + (r & 3) + 8 * (r >> 2) + 4 * hi;
                    float v;
                    if (m < 49)
                        v = st2[tm][tn][r] + b2f(Bt[((w * 49 + m) << 6) + nn])
                                           + b2f(sMask[(m << 6) + nn]);
                    else
                        v = -1.0e30f;     // padded keys
                    st2[tm][tn][r] = v;
                    mx = fmaxf(mx, v);
                }
            mx = fmaxf(mx, __shfl_xor(mx, 32));
            float sm = 0.f;
#pragma unroll
            for (int tm = 0; tm < 2; ++tm)
#pragma unroll
                for (int r = 0; r < 16; ++r) {
                    float p = __expf(st2[tm][tn][r] - mx);
                    st2[tm][tn][r] = p;
                    sm += p;
                }
            sm += __shfl_xor(sm, 32);
            float inv = 1.0f / sm;
#pragma unroll
            for (int tm = 0; tm < 2; ++tm)
#pragma unroll
                for (int r = 0; r < 16; ++r) st2[tm][tn][r] *= inv;
        }
        // PV (transposed): OH^T[dd][n] = V^T · P^T. P-frags straight from acc.
        f32x16 oh0, oh1;
#pragma unroll
        for (int i2 = 0; i2 < 16; ++i2) { oh0[i2] = 0.f; oh1[i2] = 0.f; }
#pragma unroll
        for (int ks = 0; ks < 4; ++ks) {
            bf16x8 vf = ld8(sVt, swzoff(32 * w + l31, (16 * ks + 8 * hi) * 2, 128));
            const int tm = ks >> 1, q = 8 * (ks & 1);
#pragma unroll
            for (int tn = 0; tn < 2; ++tn) {
                unsigned A0 = pk2(st2[tm][tn][q + 0], st2[tm][tn][q + 1]);
                unsigned A1 = pk2(st2[tm][tn][q + 2], st2[tm][tn][q + 3]);
                unsigned B0 = pk2(st2[tm][tn][q + 4], st2[tm][tn][q + 5]);
                unsigned B1 = pk2(st2[tm][tn][q + 6], st2[tm][tn][q + 7]);
                unsigned pA0 = (unsigned)__shfl_xor((int)A0, 32);
                unsigned pA1 = (unsigned)__shfl_xor((int)A1, 32);
                unsigned pB0 = (unsigned)__shfl_xor((int)B0, 32);
                unsigned pB1 = (unsigned)__shfl_xor((int)B1, 32);
                union { unsigned u[4]; bf16x8 v; } pf;
                pf.u[0] = hi ? pB0 : A0;
                pf.u[1] = hi ? pB1 : A1;
                pf.u[2] = hi ? B0  : pA0;
                pf.u[3] = hi ? B1  : pA1;
                if (tn == 0) oh0 = mfma16(vf, pf.v, oh0);
                else         oh1 = mfma16(vf, pf.v, oh1);
            }
        }
        // write OH row-major [n][ci] into sXO (X is dead)
#pragma unroll
        for (int g = 0; g < 4; ++g) {
            int ci0 = 32 * w + 8 * g + 4 * hi;
            st64(sXO, swzoff(l31, ci0 * 2, 256),
                 pk2(oh0[4*g+0], oh0[4*g+1]), pk2(oh0[4*g+2], oh0[4*g+3]));
            st64(sXO, swzoff(32 + l31, ci0 * 2, 256),
                 pk2(oh1[4*g+0], oh1[4*g+1]), pk2(oh1[4*g+2], oh1[4*g+3]));
        }
        __syncthreads();

        // ---- phase D: proj. OUT[n][co] = OH·Pw^T, wave w -> co-tile w -----
        f32x16 po0, po1;
#pragma unroll
        for (int i2 = 0; i2 < 16; ++i2) { po0[i2] = 0.f; po1[i2] = 0.f; }
#pragma unroll
        for (int kc = 0; kc < 8; ++kc) {
            bf16x8 pw = *reinterpret_cast<const bf16x8*>(Pr + kc * 16);
            unsigned cb = (16 * kc + 8 * hi) * 2;
            bf16x8 o0 = ld8(sXO, swzoff(l31,      cb, 256));
            bf16x8 o1 = ld8(sXO, swzoff(32 + l31, cb, 256));
            po0 = mfma16(o0, pw, po0);
            po1 = mfma16(o1, pw, po1);
        }
        {
            float pbv = sPB[32 * w + l31];
            float* og = out + (size_t)bi * 6272 + 32 * w + l31;
#pragma unroll
            for (int r = 0; r < 16; ++r) {
                int n0 = (r & 3) + 8 * (r >> 2) + 4 * hi;   // < 32
                og[(size_t)n0 * 128] = po0[r] + pbv;
                int n1 = 32 + n0;
                if (n1 < 49) og[(size_t)n1 * 128] = po1[r] + pbv;
            }
        }
    }
}

extern "C" void kernel_launch(void* const* d_in, const int* in_sizes, int n_in,
                              void* d_out, int out_size, void* d_ws, size_t ws_size,
                              hipStream_t stream) {
    const float* x      = (const float*)d_in[0];
    const float* mask   = (const float*)d_in[1];
    const float* qkv_w  = (const float*)d_in[2];
    const float* qkv_b  = (const float*)d_in[3];
    const float* proj_w = (const float*)d_in[4];
    const float* proj_b = (const float*)d_in[5];
    const float* btab   = (const float*)d_in[6];

    unsigned short* Wb = (unsigned short*)d_ws;       // 49152 bf16
    unsigned short* Pb = Wb + 49152;                  // 16384 bf16
    unsigned short* Bt = Pb + 16384;                  // 4*49*64 bf16

    wa_pre<<<306, 256, 0, stream>>>(qkv_w, proj_w, btab, Wb, Pb, Bt);
    wa_main<<<2048, 256, 0, stream>>>(x, mask, qkv_b, proj_b, Wb, Pb, Bt,
                                      (float*)d_out);
}